// Round 7
// baseline (647.447 us; speedup 1.0000x reference)
//
#include <hip/hip_runtime.h>
#include <math.h>

#define N_NODES 25000
#define N_EDGES 400000
#define HID 128
#define EDGE_F 16
#define ADY 64
#define INNER 160
#define MSG_F 273
#define HEADS 8

// element offsets inside d_out (h2 | coords | res2)
#define OUT_CRD (N_NODES * HID)
#define OUT_RES (N_NODES * (HID + 3))

// ws byte offsets (16-aligned)
#define FLAG_OFF 0
#define DEN_OFF  256
#define CACC_OFF 800256
#define HAGG_OFF 1100288
#define CW_BASE  13900288            // canonical bf16 flat weights
#define MEMSET_BYTES 13900288

typedef unsigned short u16;
typedef unsigned int u32;
typedef unsigned long long u64;
typedef __attribute__((ext_vector_type(8))) short short8;
typedef __attribute__((ext_vector_type(4))) float f32x4;

__device__ __forceinline__ float bf2f(u16 v) {
    union { u32 u; float f; } x; x.u = ((u32)v) << 16; return x.f;
}
__device__ __forceinline__ u16 f2bf(float f) {
    union { float ff; u32 u; } x; x.ff = f;
    u32 u = x.u;
    u32 rounding = 0x7FFFu + ((u >> 16) & 1u);
    u += rounding;
    return (u16)(u >> 16);
}
__device__ __forceinline__ float silu(float z) {
    z = fminf(fmaxf(z, -30000.f), 30000.f);
    return z / (1.0f + __expf(-z));
}

template<bool F32> __device__ __forceinline__ float ldg1(const void* p, size_t i) {
    if (F32) return ((const float*)p)[i];
    return bf2f(((const u16*)p)[i]);
}
template<bool F32> __device__ __forceinline__ void stg1(void* p, size_t i, float v) {
    if (F32) ((float*)p)[i] = v;
    else     ((u16*)p)[i] = f2bf(v);
}
// 8-element A-fragment load: global -> bf16 short8
template<bool F32> __device__ __forceinline__ short8 ldfragA(const void* p, size_t i) {
    if (F32) {
        const float4* fp = (const float4*)((const float*)p + i);
        float4 v0 = fp[0], v1 = fp[1];
        union { u16 s[8]; short8 v; } u;
        u.s[0]=f2bf(v0.x); u.s[1]=f2bf(v0.y); u.s[2]=f2bf(v0.z); u.s[3]=f2bf(v0.w);
        u.s[4]=f2bf(v1.x); u.s[5]=f2bf(v1.y); u.s[6]=f2bf(v1.z); u.s[7]=f2bf(v1.w);
        return u.v;
    } else {
        return *(const short8*)((const u16*)p + i);
    }
}
__device__ __forceinline__ float ldany(const void* p, size_t i, bool f32) {
    return f32 ? ((const float*)p)[i] : bf2f(((const u16*)p)[i]);
}
// wave-level LDS fence: order prior ds_writes before subsequent ds_reads,
// without s_barrier (no vmcnt drain, no inter-wave sync).
__device__ __forceinline__ void wave_lds_fence() {
    __builtin_amdgcn_wave_barrier();
    __builtin_amdgcn_s_waitcnt(0xc07f);   // lgkmcnt(0) only
    __builtin_amdgcn_wave_barrier();
}

// ---------------------------------------------------------------------------
// dtype detector (flag=1 -> fp32 inputs)
// ---------------------------------------------------------------------------
__global__ void detect_kernel(const void* h, int* flag) {
    __shared__ float red[256];
    const int t = threadIdx.x;
    const u16* p = (const u16*)h;
    float mx = 0.f;
    for (int i = 0; i < 8; i++) {
        int idx = (t * 8 + i) * 97;
        float v = fabsf(bf2f(p[idx * 2]));
        mx = fmaxf(mx, v);
    }
    red[t] = mx;
    __syncthreads();
    for (int s = 128; s > 0; s >>= 1) {
        if (t < s) red[t] = fmaxf(red[t], red[t + s]);
        __syncthreads();
    }
    if (t == 0) flag[0] = (red[0] > 1e10f || red[0] == 0.f) ? 1 : 0;
}

// ---------------------------------------------------------------------------
// flat weight canonicalization: 16 tensors -> bf16 copies in ws
// ---------------------------------------------------------------------------
struct CvtArgs {
    const void* src[16];
    u64 dstoff[16];
    int n[16];
};
__global__ void cvt_kernel(const int* __restrict__ flag, char* wsbase, CvtArgs args) {
    const int ten = blockIdx.y;
    const void* s = args.src[ten];
    u16* d = (u16*)(wsbase + args.dstoff[ten]);
    const int n = args.n[ten];
    const bool f32 = (*flag != 0);
    if (f32) {
        const float* sf = (const float*)s;
        for (int i = blockIdx.x * 256 + threadIdx.x; i < n; i += gridDim.x * 256)
            d[i] = f2bf(sf[i]);
    } else {
        const u16* su = (const u16*)s;
        for (int i = blockIdx.x * 256 + threadIdx.x; i < n; i += gridDim.x * 256)
            d[i] = su[i];
    }
}

// ---------------------------------------------------------------------------
// blocked/transposed [n][72] weight builder for all MFMA GEMMs
// ---------------------------------------------------------------------------
__global__ void blockw_kernel(const int* __restrict__ flag, char* ws,
                              u64 b1off, u64 b2off, u64 b3off, u64 b4off,
                              u64 b5off, u64 b6off, u64 b7off, u64 b8off,
                              const void* We1, const void* We2,
                              const void* Wv, const void* Wa, const void* Wc,
                              const void* Wo, const void* Wn1, const void* Wn2,
                              const void* Wf1, const void* Wf2)
{
    const bool f32 = (*flag != 0);
    u16* b1 = (u16*)(ws + b1off);
    u16* b2 = (u16*)(ws + b2off);
    u16* b3 = (u16*)(ws + b3off);
    u16* b4 = (u16*)(ws + b4off);
    u16* b5 = (u16*)(ws + b5off);
    u16* b6 = (u16*)(ws + b6off);
    u16* b7 = (u16*)(ws + b7off);
    u16* b8 = (u16*)(ws + b8off);
    const int g = blockIdx.x * 256 + threadIdx.x;
    const int stride = gridDim.x * 256;
    for (int i = g; i < 5*160*72; i += stride) {
        int c = i / (160*72), rem = i % (160*72), n = rem / 72, kc = rem % 72;
        int k = c*64 + kc;
        float v = 0.f;
        if (kc < 64) {
            if (k < MSG_F)      v = ldany(We1, (size_t)k*INNER + n, f32);
            else if (k == 273)  v = ldany(We1, (size_t)256*INNER + n, f32);
        }
        b1[i] = f2bf(v);
    }
    for (int i = g; i < 3*160*72; i += stride) {
        int c = i / (160*72), rem = i % (160*72), n = rem / 72, kc = rem % 72;
        int k = c*64 + kc;
        float v = 0.f;
        if (kc < 64 && k < INNER) v = ldany(We2, (size_t)k*INNER + n, f32);
        b2[i] = f2bf(v);
    }
    for (int i = g; i < 3*144*72; i += stride) {
        int c = i / (144*72), rem = i % (144*72), n = rem / 72, kc = rem % 72;
        int k = c*64 + kc;
        float v = 0.f;
        if (kc < 64 && k < INNER) {
            if (n < 128)      v = ldany(Wv, (size_t)k*HID + n, f32);
            else if (n < 136) v = ldany(Wa, (size_t)k*HEADS + (n-128), f32);
            else if (n == 136) v = ldany(Wc, (size_t)k, f32);
        }
        b3[i] = f2bf(v);
    }
    for (int i = g; i < 2*128*72; i += stride) {
        int c = i / (128*72), rem = i % (128*72), n = rem / 72, kc = rem % 72;
        int k = c*64 + kc;
        float v = (kc < 64 && k < HID) ? ldany(Wo, (size_t)k*HID + n, f32) : 0.f;
        b4[i] = f2bf(v);
    }
    for (int i = g; i < 2*160*72; i += stride) {
        int c = i / (160*72), rem = i % (160*72), n = rem / 72, kc = rem % 72;
        int k = c*64 + kc;
        float v = (kc < 64) ? ldany(Wn1, (size_t)k*INNER + n, f32) : 0.f;
        b5[i] = f2bf(v);
    }
    for (int i = g; i < 3*128*72; i += stride) {
        int c = i / (128*72), rem = i % (128*72), n = rem / 72, kc = rem % 72;
        int k = c*64 + kc;
        float v = (kc < 64 && k < INNER) ? ldany(Wn2, (size_t)k*HID + n, f32) : 0.f;
        b6[i] = f2bf(v);
    }
    for (int i = g; i < 256*72; i += stride) {
        int n = i / 72, kc = i % 72;
        float v = (kc < 64) ? ldany(Wf1, (size_t)kc*256 + n, f32) : 0.f;
        b7[i] = f2bf(v);
    }
    for (int i = g; i < 256*72; i += stride) {
        int n = i / 72, kc = i % 72;
        float v = (kc < 64) ? ldany(Wf2, (size_t)kc*256 + n, f32) : 0.f;
        b8[i] = f2bf(v);
    }
}

// ---------------------------------------------------------------------------
// Barrier-free MFMA edge kernel. Block = 64 edges; wave w owns edges
// [e0+16w, e0+16w+16) end-to-end. A-fragments per-lane from global; B from
// global (L1/L2); C->A transposes via per-wave LDS scratch + wave fence.
// ---------------------------------------------------------------------------
template<bool F32>
__device__ __forceinline__ void edge_body(
    const void* h, const void* coords, const void* a,
    const int* __restrict__ src, const int* __restrict__ dst,
    const u16* __restrict__ We1Tb, const u16* __restrict__ We2Tb,
    const u16* __restrict__ W3Tb,
    const u16* __restrict__ cbe1, const u16* __restrict__ cbe2,
    float* __restrict__ den, float* __restrict__ hagg, float* __restrict__ cacc,
    u16* sScr)
{
    const int t   = threadIdx.x;
    const int w   = t >> 6;
    const int l   = t & 63;
    const int col = l & 15;
    const int q   = l >> 4;
    const int ebase = blockIdx.x * 64 + w * 16;

    u16* sc = sScr + w * 16 * 168;     // per-wave scratch [16][168]

    // A-row edge (row = col)
    const int myedge = ebase + col;
    const int s_col = src[myedge];
    const int d_col = dst[myedge];
    // radial for my A-row edge
    float r2col;
    {
        float dx = ldg1<F32>(coords, (size_t)s_col*3+0) - ldg1<F32>(coords, (size_t)d_col*3+0);
        float dy = ldg1<F32>(coords, (size_t)s_col*3+1) - ldg1<F32>(coords, (size_t)d_col*3+1);
        float dz = ldg1<F32>(coords, (size_t)s_col*3+2) - ldg1<F32>(coords, (size_t)d_col*3+2);
        r2col = dx*dx + dy*dy + dz*dz;
    }
    // C-row (epilogue) edges: m = q*4+r
    int dstep[4];
    #pragma unroll
    for (int r = 0; r < 4; r++) dstep[r] = dst[ebase + q*4 + r];

    // ---- GEMM1: K=320 (5 chunks x 2 ks) ----
    f32x4 acc1[10];
    #pragma unroll
    for (int nt = 0; nt < 10; nt++) {
        float v = bf2f(cbe1[nt*16 + col]);
        acc1[nt] = (f32x4){v, v, v, v};
    }
    #pragma unroll
    for (int c = 0; c < 4; c++) {
        const int node = (c < 2) ? s_col : d_col;
        #pragma unroll
        for (int ks = 0; ks < 2; ks++) {
            short8 af = ldfragA<F32>(h, (size_t)node*HID + (c&1)*64 + ks*32 + q*8);
            const u16* B1 = We1Tb + (size_t)c*160*72 + ks*32 + q*8;
            #pragma unroll
            for (int nt = 0; nt < 10; nt++) {
                short8 b = *(const short8*)(B1 + (nt*16 + col)*72);
                acc1[nt] = __builtin_amdgcn_mfma_f32_16x16x32_bf16(af, b, acc1[nt], 0, 0, 0);
            }
        }
    }
    {   // c == 4: feature chunk (radial_hi, a[0..15], radial_lo, zeros)
        float r2hi = bf2f(f2bf(r2col));
        float r2lo = r2col - r2hi;
        #pragma unroll
        for (int ks = 0; ks < 2; ks++) {
            union { u16 s[8]; short8 v; } u;
            #pragma unroll
            for (int j = 0; j < 8; j++) {
                int f = ks*32 + q*8 + j;
                float av = (f >= 1 && f <= 16)
                         ? ldg1<F32>(a, (size_t)myedge*EDGE_F + (f-1)) : 0.f;
                float fv = (f == 0) ? r2col : (f == 17) ? r2lo : av;
                u.s[j] = f2bf(fv);
            }
            const u16* B1 = We1Tb + (size_t)4*160*72 + ks*32 + q*8;
            #pragma unroll
            for (int nt = 0; nt < 10; nt++) {
                short8 b = *(const short8*)(B1 + (nt*16 + col)*72);
                acc1[nt] = __builtin_amdgcn_mfma_f32_16x16x32_bf16(u.v, b, acc1[nt], 0, 0, 0);
            }
        }
    }
    // silu -> m1 (C-layout write to wave scratch)
    #pragma unroll
    for (int nt = 0; nt < 10; nt++)
        #pragma unroll
        for (int r = 0; r < 4; r++)
            sc[(q*4 + r)*168 + nt*16 + col] = f2bf(silu(acc1[nt][r]));
    wave_lds_fence();

    // ---- GEMM2: K=160 ----
    f32x4 acc2[10];
    #pragma unroll
    for (int nt = 0; nt < 10; nt++) {
        float v = bf2f(cbe2[nt*16 + col]);
        acc2[nt] = (f32x4){v, v, v, v};
    }
    #pragma unroll
    for (int k5 = 0; k5 < 5; k5++) {
        short8 af = *(const short8*)(sc + col*168 + k5*32 + q*8);
        const u16* B2 = We2Tb + (size_t)(k5>>1)*160*72 + (k5&1)*32 + q*8;
        #pragma unroll
        for (int nt = 0; nt < 10; nt++) {
            short8 b = *(const short8*)(B2 + (nt*16 + col)*72);
            acc2[nt] = __builtin_amdgcn_mfma_f32_16x16x32_bf16(af, b, acc2[nt], 0, 0, 0);
        }
    }
    // silu -> m2 (reuse scratch; program order guarantees reads done)
    #pragma unroll
    for (int nt = 0; nt < 10; nt++)
        #pragma unroll
        for (int r = 0; r < 4; r++)
            sc[(q*4 + r)*168 + nt*16 + col] = f2bf(silu(acc2[nt][r]));
    wave_lds_fence();

    // ---- GEMM3: N=144, K=160 ----
    f32x4 acc3[9];
    #pragma unroll
    for (int nt = 0; nt < 9; nt++) acc3[nt] = (f32x4){0.f, 0.f, 0.f, 0.f};
    #pragma unroll
    for (int k5 = 0; k5 < 5; k5++) {
        short8 af = *(const short8*)(sc + col*168 + k5*32 + q*8);
        const u16* B3 = W3Tb + (size_t)(k5>>1)*144*72 + (k5&1)*32 + q*8;
        #pragma unroll
        for (int nt = 0; nt < 9; nt++) {
            short8 b = *(const short8*)(B3 + (nt*16 + col)*72);
            acc3[nt] = __builtin_amdgcn_mfma_f32_16x16x32_bf16(af, b, acc3[nt], 0, 0, 0);
        }
    }

    // ---- epilogue ----
    float exv[4] = {0.f, 0.f, 0.f, 0.f};
    if (col < 8) {           // logits: head=col, cols 128..135
        #pragma unroll
        for (int r = 0; r < 4; r++) {
            float ex = __expf(fminf(fmaxf(acc3[8][r], -30.f), 30.f));
            exv[r] = ex;
            atomicAdd(&den[(size_t)dstep[r]*8 + col], ex);
        }
    } else if (col == 8) {   // coord scalar: col 136
        #pragma unroll
        for (int r = 0; r < 4; r++) {
            int e = ebase + q*4 + r;
            int ss = src[e], dd = dstep[r];
            float dx = ldg1<F32>(coords, (size_t)ss*3+0) - ldg1<F32>(coords, (size_t)dd*3+0);
            float dy = ldg1<F32>(coords, (size_t)ss*3+1) - ldg1<F32>(coords, (size_t)dd*3+1);
            float dz = ldg1<F32>(coords, (size_t)ss*3+2) - ldg1<F32>(coords, (size_t)dd*3+2);
            float r2 = dx*dx + dy*dy + dz*dz;
            float invf = 1.0f / (sqrtf(r2 + 1e-5f) + 1.0f);
            float lc = fminf(fmaxf(acc3[8][r], -1e6f), 1e6f) * invf;
            atomicAdd(&cacc[(size_t)dd*3 + 0], lc * dx);
            atomicAdd(&cacc[(size_t)dd*3 + 1], lc * dy);
            atomicAdd(&cacc[(size_t)dd*3 + 2], lc * dz);
        }
    }
    // share ex via shfl (source lane q*16+nt holds head nt for rows q*4+r)
    #pragma unroll
    for (int nt = 0; nt < 8; nt++) {
        float e0 = __shfl(exv[0], q*16 + nt);
        float e1 = __shfl(exv[1], q*16 + nt);
        float e2 = __shfl(exv[2], q*16 + nt);
        float e3 = __shfl(exv[3], q*16 + nt);
        atomicAdd(&hagg[(size_t)dstep[0]*HID + nt*16 + col], acc3[nt][0] * e0);
        atomicAdd(&hagg[(size_t)dstep[1]*HID + nt*16 + col], acc3[nt][1] * e1);
        atomicAdd(&hagg[(size_t)dstep[2]*HID + nt*16 + col], acc3[nt][2] * e2);
        atomicAdd(&hagg[(size_t)dstep[3]*HID + nt*16 + col], acc3[nt][3] * e3);
    }
}

__global__ __launch_bounds__(256, 4)
void edge_kernel(const int* __restrict__ flag,
                 const void* h, const void* coords, const void* a,
                 const int* __restrict__ src, const int* __restrict__ dst,
                 const u16* __restrict__ We1Tb, const u16* __restrict__ We2Tb,
                 const u16* __restrict__ W3Tb,
                 const u16* __restrict__ cbe1, const u16* __restrict__ cbe2,
                 float* __restrict__ den, float* __restrict__ hagg,
                 float* __restrict__ cacc)
{
    __shared__ __align__(16) u16 sScr[4 * 16 * 168];   // 21504 B
    if (*flag)
        edge_body<true>(h, coords, a, src, dst, We1Tb, We2Tb, W3Tb, cbe1, cbe2,
                        den, hagg, cacc, sScr);
    else
        edge_body<false>(h, coords, a, src, dst, We1Tb, We2Tb, W3Tb, cbe1, cbe2,
                         den, hagg, cacc, sScr);
}

// ---------------------------------------------------------------------------
// Barrier-free fused MFMA node kernel. Block = 64 nodes; wave w owns nodes
// [n0+16w, n0+16w+16) end-to-end.
// ---------------------------------------------------------------------------
template<bool F32>
__device__ __forceinline__ void node_body(
    const void* h, const void* res, const void* coords, const void* y,
    const float* __restrict__ den, const float* __restrict__ hagg,
    const float* __restrict__ cacc,
    const u16* __restrict__ WoB, const u16* __restrict__ Wn1B,
    const u16* __restrict__ Wn2B, const u16* __restrict__ Wf1B,
    const u16* __restrict__ Wf2B,
    const u16* __restrict__ cbn1, const u16* __restrict__ cbn2,
    const u16* __restrict__ cbf1, const u16* __restrict__ cbf2,
    void* out, u16* sScr)
{
    const int t = threadIdx.x;
    const int w = t >> 6, l = t & 63, col = l & 15, q = l >> 4;
    const int nodew = blockIdx.x * 64 + w * 16;
    const int mynode = nodew + col;           // A-row node
    const bool okA = mynode < N_NODES;
    u16* sc = sScr + w * 16 * 168;

    int gm[4]; bool okC[4];
    #pragma unroll
    for (int r = 0; r < 4; r++) { gm[r] = nodew + q*4 + r; okC[r] = gm[r] < N_NODES; }

    // ---- GEMM Wo: f2 = g @ Wo, K=128 ----
    f32x4 aF2[8];
    #pragma unroll
    for (int nt = 0; nt < 8; nt++) aF2[nt] = (f32x4){0.f,0.f,0.f,0.f};
    #pragma unroll
    for (int c = 0; c < 2; c++) {
        #pragma unroll
        for (int ks = 0; ks < 2; ks++) {
            const int kbase = c*64 + ks*32 + q*8;
            union { u16 s[8]; short8 v; } u;
            if (okA) {
                float dd = den[(size_t)mynode*8 + (kbase >> 4)];
                float inv = dd > 0.f ? 1.f/dd : 0.f;
                const float4* gp = (const float4*)(hagg + (size_t)mynode*HID + kbase);
                float4 v0 = gp[0], v1 = gp[1];
                u.s[0]=f2bf(v0.x*inv); u.s[1]=f2bf(v0.y*inv); u.s[2]=f2bf(v0.z*inv); u.s[3]=f2bf(v0.w*inv);
                u.s[4]=f2bf(v1.x*inv); u.s[5]=f2bf(v1.y*inv); u.s[6]=f2bf(v1.z*inv); u.s[7]=f2bf(v1.w*inv);
            } else {
                #pragma unroll
                for (int j = 0; j < 8; j++) u.s[j] = 0;
            }
            const u16* B = WoB + (size_t)c*128*72 + ks*32 + q*8;
            #pragma unroll
            for (int nt = 0; nt < 8; nt++) {
                short8 b = *(const short8*)(B + (nt*16 + col)*72);
                aF2[nt] = __builtin_amdgcn_mfma_f32_16x16x32_bf16(u.v, b, aF2[nt], 0, 0, 0);
            }
        }
    }

    // ---- film1: K=64 ----
    f32x4 aFl[16];
    #pragma unroll
    for (int nt = 0; nt < 16; nt++) {
        float v = bf2f(cbf1[nt*16 + col]);
        aFl[nt] = (f32x4){v,v,v,v};
    }
    #pragma unroll
    for (int ks = 0; ks < 2; ks++) {
        short8 af;
        if (okA) af = ldfragA<F32>(y, (size_t)mynode*ADY + ks*32 + q*8);
        else { union { u16 s[8]; short8 v; } z; for (int j=0;j<8;j++) z.s[j]=0; af = z.v; }
        const u16* B = Wf1B + ks*32 + q*8;
        #pragma unroll
        for (int nt = 0; nt < 16; nt++) {
            short8 b = *(const short8*)(B + (nt*16 + col)*72);
            aFl[nt] = __builtin_amdgcn_mfma_f32_16x16x32_bf16(af, b, aFl[nt], 0, 0, 0);
        }
    }

    // ---- LN1 + res1 + h1 ----
    float h1c[8][4], r1c[8][4];
    {
        float xv[8][4], s[4], ss[4];
        #pragma unroll
        for (int r = 0; r < 4; r++) { s[r] = 0.f; ss[r] = 0.f; }
        #pragma unroll
        for (int nt = 0; nt < 8; nt++)
            #pragma unroll
            for (int r = 0; r < 4; r++) {
                float hv = okC[r] ? ldg1<F32>(h, (size_t)gm[r]*HID + nt*16 + col) : 0.f;
                float x = hv + aF2[nt][r];
                xv[nt][r] = x; s[r] += x; ss[r] += x*x;
            }
        #pragma unroll
        for (int r = 0; r < 4; r++)
            for (int off = 1; off <= 8; off <<= 1) {
                s[r]  += __shfl_xor(s[r], off);
                ss[r] += __shfl_xor(ss[r], off);
            }
        #pragma unroll
        for (int r = 0; r < 4; r++) {
            float mu = s[r] * (1.f/128.f);
            float var = ss[r] * (1.f/128.f) - mu*mu;
            float rs = rsqrtf(fmaxf(var, 0.f) + 1e-5f);
            #pragma unroll
            for (int nt = 0; nt < 8; nt++) {
                float h1 = (xv[nt][r]-mu)*rs*(1.f+aFl[nt][r]) + aFl[nt+8][r];
                h1c[nt][r] = h1;
                float rv = okC[r] ? ldg1<F32>(res, (size_t)gm[r]*HID + nt*16 + col) : 0.f;
                r1c[nt][r] = rv + aF2[nt][r];
                sc[(q*4 + r)*168 + nt*16 + col] = f2bf(h1);
            }
        }
    }
    wave_lds_fence();

    // ---- n1 GEMM: t = silu(h1@Wn1+bn1), K=128 ----
    f32x4 aT[10];
    #pragma unroll
    for (int nt = 0; nt < 10; nt++) {
        float v = bf2f(cbn1[nt*16 + col]);
        aT[nt] = (f32x4){v,v,v,v};
    }
    #pragma unroll
    for (int c = 0; c < 2; c++) {
        #pragma unroll
        for (int ks = 0; ks < 2; ks++) {
            short8 af = *(const short8*)(sc + col*168 + c*64 + ks*32 + q*8);
            const u16* B = Wn1B + (size_t)c*160*72 + ks*32 + q*8;
            #pragma unroll
            for (int nt = 0; nt < 10; nt++) {
                short8 b = *(const short8*)(B + (nt*16 + col)*72);
                aT[nt] = __builtin_amdgcn_mfma_f32_16x16x32_bf16(af, b, aT[nt], 0, 0, 0);
            }
        }
    }
    #pragma unroll
    for (int nt = 0; nt < 10; nt++)
        #pragma unroll
        for (int r = 0; r < 4; r++)
            sc[(q*4 + r)*168 + nt*16 + col] = f2bf(silu(aT[nt][r]));
    wave_lds_fence();

    // ---- n2 GEMM: f3 = t@Wn2+bn2, K=160 ----
    f32x4 aF3[8];
    #pragma unroll
    for (int nt = 0; nt < 8; nt++) {
        float v = bf2f(cbn2[nt*16 + col]);
        aF3[nt] = (f32x4){v,v,v,v};
    }
    #pragma unroll
    for (int k5 = 0; k5 < 5; k5++) {
        short8 af = *(const short8*)(sc + col*168 + k5*32 + q*8);
        const u16* B = Wn2B + (size_t)(k5>>1)*128*72 + (k5&1)*32 + q*8;
        #pragma unroll
        for (int nt = 0; nt < 8; nt++) {
            short8 b = *(const short8*)(B + (nt*16 + col)*72);
            aF3[nt] = __builtin_amdgcn_mfma_f32_16x16x32_bf16(af, b, aF3[nt], 0, 0, 0);
        }
    }

    // ---- film2: K=64 ----
    #pragma unroll
    for (int nt = 0; nt < 16; nt++) {
        float v = bf2f(cbf2[nt*16 + col]);
        aFl[nt] = (f32x4){v,v,v,v};
    }
    #pragma unroll
    for (int ks = 0; ks < 2; ks++) {
        short8 af;
        if (okA) af = ldfragA<F32>(y, (size_t)mynode*ADY + ks*32 + q*8);
        else { union { u16 s[8]; short8 v; } z; for (int j=0;j<8;j++) z.s[j]=0; af = z.v; }
        const u16* B = Wf2B + ks*32 + q*8;
        #pragma unroll
        for (int nt = 0; nt < 16; nt++) {
            short8 b = *(const short8*)(B + (nt*16 + col)*72);
            aFl[nt] = __builtin_amdgcn_mfma_f32_16x16x32_bf16(af, b, aFl[nt], 0, 0, 0);
        }
    }

    // ---- LN2 + h2/res2 ----
    {
        float xv[8][4], s[4], ss[4];
        #pragma unroll
        for (int r = 0; r < 4; r++) { s[r] = 0.f; ss[r] = 0.f; }
        #pragma unroll
        for (int nt = 0; nt < 8; nt++)
            #pragma unroll
            for (int r = 0; r < 4; r++) {
                float x = h1c[nt][r] + aF3[nt][r];
                xv[nt][r] = x; s[r] += x; ss[r] += x*x;
            }
        #pragma unroll
        for (int r = 0; r < 4; r++)
            for (int off = 1; off <= 8; off <<= 1) {
                s[r]  += __shfl_xor(s[r], off);
                ss[r] += __shfl_xor(ss[r], off);
            }
        #pragma unroll
        for (int r = 0; r < 4; r++) {
            float mu = s[r] * (1.f/128.f);
            float var = ss[r] * (1.f/128.f) - mu*mu;
            float rs = rsqrtf(fmaxf(var, 0.f) + 1e-5f);
            if (okC[r]) {
                #pragma unroll
                for (int nt = 0; nt < 8; nt++) {
                    int n = nt*16 + col;
                    float h2 = (xv[nt][r]-mu)*rs*(1.f+aFl[nt][r]) + aFl[nt+8][r];
                    stg1<F32>(out, (size_t)gm[r]*HID + n, h2);
                    stg1<F32>(out, (size_t)OUT_RES + (size_t)gm[r]*HID + n,
                              r1c[nt][r] + aF3[nt][r]);
                }
            }
        }
    }

    // ---- coords (q==0 lanes, one node each) ----
    if (q == 0 && okA) {
        #pragma unroll
        for (int j = 0; j < 3; j++)
            stg1<F32>(out, (size_t)OUT_CRD + (size_t)mynode*3 + j,
                      ldg1<F32>(coords, (size_t)mynode*3 + j) + cacc[(size_t)mynode*3 + j]);
    }
}

__global__ __launch_bounds__(256, 2)
void node_kernel(const int* __restrict__ flag,
                 const void* h, const void* res, const void* coords, const void* y,
                 const float* __restrict__ den, const float* __restrict__ hagg,
                 const float* __restrict__ cacc,
                 const u16* __restrict__ WoB, const u16* __restrict__ Wn1B,
                 const u16* __restrict__ Wn2B, const u16* __restrict__ Wf1B,
                 const u16* __restrict__ Wf2B,
                 const u16* __restrict__ cbn1, const u16* __restrict__ cbn2,
                 const u16* __restrict__ cbf1, const u16* __restrict__ cbf2,
                 void* out)
{
    __shared__ __align__(16) u16 sScr[4 * 16 * 168];   // 21504 B
    if (*flag)
        node_body<true>(h, res, coords, y, den, hagg, cacc, WoB, Wn1B, Wn2B,
                        Wf1B, Wf2B, cbn1, cbn2, cbf1, cbf2, out, sScr);
    else
        node_body<false>(h, res, coords, y, den, hagg, cacc, WoB, Wn1B, Wn2B,
                         Wf1B, Wf2B, cbn1, cbn2, cbf1, cbf2, out, sScr);
}

// ---------------------------------------------------------------------------
extern "C" void kernel_launch(void* const* d_in, const int* in_sizes, int n_in,
                              void* d_out, int out_size, void* d_ws, size_t ws_size,
                              hipStream_t stream)
{
    const void* h      = d_in[0];
    const void* coords = d_in[1];
    const void* a      = d_in[2];
    const void* y      = d_in[3];
    const void* res    = d_in[4];
    const int* src     = (const int*)d_in[5];
    const int* dst     = (const int*)d_in[6];

    char* ws = (char*)d_ws;
    int*   flag = (int*)(ws + FLAG_OFF);
    float* den  = (float*)(ws + DEN_OFF);
    float* cacc = (float*)(ws + CACC_OFF);
    float* hagg = (float*)(ws + HAGG_OFF);

    const int wn[16]  = {43680, 25600, 20480, 1280, 160, 160, 160, 16384,
                         20480, 160, 20480, 128, 16384, 256, 16384, 256};
    const int widx[16] = {7, 9, 12, 13, 11, 8, 10, 14, 15, 16, 17, 18, 19, 20, 21, 22};
    u64 off = CW_BASE;
    CvtArgs args;
    u64 offs[16];
    for (int i = 0; i < 16; i++) {
        args.src[i] = d_in[widx[i]];
        args.dstoff[i] = off;
        args.n[i] = wn[i];
        offs[i] = off;
        off += (u64)wn[i] * 2;
    }
    u64 bw1 = (off + 255) & ~(u64)255;
    u64 bw2 = bw1 + (u64)5*160*72*2;
    u64 bw3 = bw2 + (u64)3*160*72*2;
    u64 bw4 = bw3 + (u64)3*144*72*2;
    u64 bw5 = bw4 + (u64)2*128*72*2;
    u64 bw6 = bw5 + (u64)2*160*72*2;
    u64 bw7 = bw6 + (u64)3*128*72*2;
    u64 bw8 = bw7 + (u64)256*72*2;

    const u16* cbe1 = (const u16*)(ws + offs[5]);
    const u16* cbe2 = (const u16*)(ws + offs[6]);
    const u16* cbn1 = (const u16*)(ws + offs[9]);
    const u16* cbn2 = (const u16*)(ws + offs[11]);
    const u16* cbf1 = (const u16*)(ws + offs[13]);
    const u16* cbf2 = (const u16*)(ws + offs[15]);
    const u16* We1Tb = (const u16*)(ws + bw1);
    const u16* We2Tb = (const u16*)(ws + bw2);
    const u16* W3Tb  = (const u16*)(ws + bw3);
    const u16* WoB   = (const u16*)(ws + bw4);
    const u16* Wn1B  = (const u16*)(ws + bw5);
    const u16* Wn2B  = (const u16*)(ws + bw6);
    const u16* Wf1B  = (const u16*)(ws + bw7);
    const u16* Wf2B  = (const u16*)(ws + bw8);

    hipMemsetAsync(d_ws, 0, MEMSET_BYTES, stream);

    detect_kernel<<<1, 256, 0, stream>>>(h, flag);
    cvt_kernel<<<dim3(8, 16), 256, 0, stream>>>(flag, ws, args);
    blockw_kernel<<<64, 256, 0, stream>>>(flag, ws, bw1, bw2, bw3, bw4,
                                          bw5, bw6, bw7, bw8,
                                          d_in[7], d_in[9], d_in[12], d_in[13], d_in[11],
                                          d_in[14], d_in[15], d_in[17], d_in[19], d_in[21]);

    edge_kernel<<<N_EDGES/64, 256, 0, stream>>>(flag, h, coords, a, src, dst,
                                                We1Tb, We2Tb, W3Tb, cbe1, cbe2,
                                                den, hagg, cacc);

    node_kernel<<<(N_NODES + 63)/64, 256, 0, stream>>>(
        flag, h, res, coords, y, den, hagg, cacc,
        WoB, Wn1B, Wn2B, Wf1B, Wf2B, cbn1, cbn2, cbf1, cbf2, d_out);
}

// Round 8
// 581.988 us; speedup vs baseline: 1.1125x; 1.1125x over previous
//
#include <hip/hip_runtime.h>
#include <math.h>

#define N_NODES 25000
#define N_EDGES 400000
#define HID 128
#define EDGE_F 16
#define ADY 64
#define INNER 160
#define MSG_F 273
#define HEADS 8

// element offsets inside d_out (h2 | coords | res2)
#define OUT_CRD (N_NODES * HID)
#define OUT_RES (N_NODES * (HID + 3))

// ws byte offsets (16-aligned)
#define FLAG_OFF 0
#define DEN_OFF  256
#define CACC_OFF 800256
#define HAGG_OFF 1100288
#define CW_BASE  13900288            // canonical bf16 flat weights
#define MEMSET_BYTES 13900288

typedef unsigned short u16;
typedef unsigned int u32;
typedef unsigned long long u64;
typedef __attribute__((ext_vector_type(8))) short short8;
typedef __attribute__((ext_vector_type(4))) float f32x4;

__device__ __forceinline__ float bf2f(u16 v) {
    union { u32 u; float f; } x; x.u = ((u32)v) << 16; return x.f;
}
__device__ __forceinline__ u16 f2bf(float f) {
    union { float ff; u32 u; } x; x.ff = f;
    u32 u = x.u;
    u32 rounding = 0x7FFFu + ((u >> 16) & 1u);
    u += rounding;
    return (u16)(u >> 16);
}
__device__ __forceinline__ float silu(float z) {
    z = fminf(fmaxf(z, -30000.f), 30000.f);
    return z / (1.0f + __expf(-z));
}

template<bool F32> __device__ __forceinline__ float ldg1(const void* p, size_t i) {
    if (F32) return ((const float*)p)[i];
    return bf2f(((const u16*)p)[i]);
}
template<bool F32> __device__ __forceinline__ void stg1(void* p, size_t i, float v) {
    if (F32) ((float*)p)[i] = v;
    else     ((u16*)p)[i] = f2bf(v);
}
// 8 contiguous elements -> bf16 into 16B-aligned LDS dst
template<bool F32> __device__ __forceinline__ void ld8a(const void* p, size_t i, u16* dst) {
    if (F32) {
        const float* fp = (const float*)p + i;
        float4 v0 = ((const float4*)fp)[0];
        float4 v1 = ((const float4*)fp)[1];
        __align__(16) u16 tmp[8] = { f2bf(v0.x), f2bf(v0.y), f2bf(v0.z), f2bf(v0.w),
                                     f2bf(v1.x), f2bf(v1.y), f2bf(v1.z), f2bf(v1.w) };
        *(uint4*)dst = *(const uint4*)tmp;
    } else {
        *(uint4*)dst = *(const uint4*)((const u16*)p + i);
    }
}
// 8-element A-fragment load: global -> bf16 short8
template<bool F32> __device__ __forceinline__ short8 ldfragA(const void* p, size_t i) {
    if (F32) {
        const float4* fp = (const float4*)((const float*)p + i);
        float4 v0 = fp[0], v1 = fp[1];
        union { u16 s[8]; short8 v; } u;
        u.s[0]=f2bf(v0.x); u.s[1]=f2bf(v0.y); u.s[2]=f2bf(v0.z); u.s[3]=f2bf(v0.w);
        u.s[4]=f2bf(v1.x); u.s[5]=f2bf(v1.y); u.s[6]=f2bf(v1.z); u.s[7]=f2bf(v1.w);
        return u.v;
    } else {
        return *(const short8*)((const u16*)p + i);
    }
}
__device__ __forceinline__ float ldany(const void* p, size_t i, bool f32) {
    return f32 ? ((const float*)p)[i] : bf2f(((const u16*)p)[i]);
}
// wave-level LDS fence: order prior ds_writes before subsequent ds_reads,
// without s_barrier (no vmcnt drain, no inter-wave sync).
__device__ __forceinline__ void wave_lds_fence() {
    __builtin_amdgcn_wave_barrier();
    __builtin_amdgcn_s_waitcnt(0xc07f);   // lgkmcnt(0) only
    __builtin_amdgcn_wave_barrier();
}

// ---------------------------------------------------------------------------
// dtype detector (flag=1 -> fp32 inputs)
// ---------------------------------------------------------------------------
__global__ void detect_kernel(const void* h, int* flag) {
    __shared__ float red[256];
    const int t = threadIdx.x;
    const u16* p = (const u16*)h;
    float mx = 0.f;
    for (int i = 0; i < 8; i++) {
        int idx = (t * 8 + i) * 97;
        float v = fabsf(bf2f(p[idx * 2]));
        mx = fmaxf(mx, v);
    }
    red[t] = mx;
    __syncthreads();
    for (int s = 128; s > 0; s >>= 1) {
        if (t < s) red[t] = fmaxf(red[t], red[t + s]);
        __syncthreads();
    }
    if (t == 0) flag[0] = (red[0] > 1e10f || red[0] == 0.f) ? 1 : 0;
}

// ---------------------------------------------------------------------------
// flat weight canonicalization: 16 tensors -> bf16 copies in ws
// ---------------------------------------------------------------------------
struct CvtArgs {
    const void* src[16];
    u64 dstoff[16];
    int n[16];
};
__global__ void cvt_kernel(const int* __restrict__ flag, char* wsbase, CvtArgs args) {
    const int ten = blockIdx.y;
    const void* s = args.src[ten];
    u16* d = (u16*)(wsbase + args.dstoff[ten]);
    const int n = args.n[ten];
    const bool f32 = (*flag != 0);
    if (f32) {
        const float* sf = (const float*)s;
        for (int i = blockIdx.x * 256 + threadIdx.x; i < n; i += gridDim.x * 256)
            d[i] = f2bf(sf[i]);
    } else {
        const u16* su = (const u16*)s;
        for (int i = blockIdx.x * 256 + threadIdx.x; i < n; i += gridDim.x * 256)
            d[i] = su[i];
    }
}

// ---------------------------------------------------------------------------
// blocked/transposed [n][72] weight builder for all MFMA GEMMs
// ---------------------------------------------------------------------------
__global__ void blockw_kernel(const int* __restrict__ flag, char* ws,
                              u64 b1off, u64 b2off, u64 b3off, u64 b4off,
                              u64 b5off, u64 b6off, u64 b7off, u64 b8off,
                              const void* We1, const void* We2,
                              const void* Wv, const void* Wa, const void* Wc,
                              const void* Wo, const void* Wn1, const void* Wn2,
                              const void* Wf1, const void* Wf2)
{
    const bool f32 = (*flag != 0);
    u16* b1 = (u16*)(ws + b1off);
    u16* b2 = (u16*)(ws + b2off);
    u16* b3 = (u16*)(ws + b3off);
    u16* b4 = (u16*)(ws + b4off);
    u16* b5 = (u16*)(ws + b5off);
    u16* b6 = (u16*)(ws + b6off);
    u16* b7 = (u16*)(ws + b7off);
    u16* b8 = (u16*)(ws + b8off);
    const int g = blockIdx.x * 256 + threadIdx.x;
    const int stride = gridDim.x * 256;
    for (int i = g; i < 5*160*72; i += stride) {
        int c = i / (160*72), rem = i % (160*72), n = rem / 72, kc = rem % 72;
        int k = c*64 + kc;
        float v = 0.f;
        if (kc < 64) {
            if (k < MSG_F)      v = ldany(We1, (size_t)k*INNER + n, f32);
            else if (k == 273)  v = ldany(We1, (size_t)256*INNER + n, f32);
        }
        b1[i] = f2bf(v);
    }
    for (int i = g; i < 3*160*72; i += stride) {
        int c = i / (160*72), rem = i % (160*72), n = rem / 72, kc = rem % 72;
        int k = c*64 + kc;
        float v = 0.f;
        if (kc < 64 && k < INNER) v = ldany(We2, (size_t)k*INNER + n, f32);
        b2[i] = f2bf(v);
    }
    for (int i = g; i < 3*144*72; i += stride) {
        int c = i / (144*72), rem = i % (144*72), n = rem / 72, kc = rem % 72;
        int k = c*64 + kc;
        float v = 0.f;
        if (kc < 64 && k < INNER) {
            if (n < 128)      v = ldany(Wv, (size_t)k*HID + n, f32);
            else if (n < 136) v = ldany(Wa, (size_t)k*HEADS + (n-128), f32);
            else if (n == 136) v = ldany(Wc, (size_t)k, f32);
        }
        b3[i] = f2bf(v);
    }
    for (int i = g; i < 2*128*72; i += stride) {
        int c = i / (128*72), rem = i % (128*72), n = rem / 72, kc = rem % 72;
        int k = c*64 + kc;
        float v = (kc < 64 && k < HID) ? ldany(Wo, (size_t)k*HID + n, f32) : 0.f;
        b4[i] = f2bf(v);
    }
    for (int i = g; i < 2*160*72; i += stride) {
        int c = i / (160*72), rem = i % (160*72), n = rem / 72, kc = rem % 72;
        int k = c*64 + kc;
        float v = (kc < 64) ? ldany(Wn1, (size_t)k*INNER + n, f32) : 0.f;
        b5[i] = f2bf(v);
    }
    for (int i = g; i < 3*128*72; i += stride) {
        int c = i / (128*72), rem = i % (128*72), n = rem / 72, kc = rem % 72;
        int k = c*64 + kc;
        float v = (kc < 64 && k < INNER) ? ldany(Wn2, (size_t)k*HID + n, f32) : 0.f;
        b6[i] = f2bf(v);
    }
    for (int i = g; i < 256*72; i += stride) {
        int n = i / 72, kc = i % 72;
        float v = (kc < 64) ? ldany(Wf1, (size_t)kc*256 + n, f32) : 0.f;
        b7[i] = f2bf(v);
    }
    for (int i = g; i < 256*72; i += stride) {
        int n = i / 72, kc = i % 72;
        float v = (kc < 64) ? ldany(Wf2, (size_t)kc*256 + n, f32) : 0.f;
        b8[i] = f2bf(v);
    }
}

// ---------------------------------------------------------------------------
// Hybrid MFMA edge kernel: R6's cooperative coalesced staging + wave-private
// LDS, with ALL block barriers replaced by wave-local lgkm fences (every LDS
// region's producer wave == consumer wave). B-fragments from global (L1/L2).
// ---------------------------------------------------------------------------
template<bool F32>
__device__ __forceinline__ void edge_body(
    const void* h, const void* coords, const void* a,
    const int* __restrict__ src, const int* __restrict__ dst,
    const u16* __restrict__ We1Tb, const u16* __restrict__ We2Tb,
    const u16* __restrict__ W3Tb,
    const u16* __restrict__ cbe1, const u16* __restrict__ cbe2,
    float* __restrict__ den, float* __restrict__ hagg, float* __restrict__ cacc,
    u16* sPool, float* sdiff, float* srad, int* ssrc, int* sdstl)
{
    const int t   = threadIdx.x;
    const int w   = t >> 6;
    const int l   = t & 63;
    const int col = l & 15;
    const int q   = l >> 4;
    const int e0  = blockIdx.x * 64;

    u16* sF  = sPool;               // [64][360]  rows wave-private
    u16* sM1 = sPool;               // [64][168]  (aliases sF)
    u16* sM2 = sPool + 64*168;      // [64][168]

    // ---- per-wave meta staging (lanes 0..15 of each wave) ----
    if (l < 16) {
        int idx = w*16 + l;
        int e = e0 + idx;
        int s = src[e], d = dst[e];
        ssrc[idx] = s; sdstl[idx] = d;
        float dx = ldg1<F32>(coords, (size_t)s*3+0) - ldg1<F32>(coords, (size_t)d*3+0);
        float dy = ldg1<F32>(coords, (size_t)s*3+1) - ldg1<F32>(coords, (size_t)d*3+1);
        float dz = ldg1<F32>(coords, (size_t)s*3+2) - ldg1<F32>(coords, (size_t)d*3+2);
        sdiff[idx*4+0] = dx; sdiff[idx*4+1] = dy; sdiff[idx*4+2] = dz;
        float r2 = dx*dx + dy*dy + dz*dz;
        srad[idx] = r2;
        sdiff[idx*4+3] = 1.0f / (sqrtf(r2 + 1e-5f) + 1.0f);
    }
    wave_lds_fence();

    // ---- stage all f chunks (4 lanes per edge, coalesced) ----
    {
        int e = t >> 2, part = t & 3;         // e in [16w, 16w+16)
        int node_s = ssrc[e], node_d = sdstl[e];
        #pragma unroll
        for (int c = 0; c < 4; c++) {
            int node = (c < 2) ? node_s : node_d;
            int c0 = (c & 1) * 64 + part * 16;
            ld8a<F32>(h, (size_t)node*HID + c0,     &sF[e*360 + c*72 + part*16]);
            ld8a<F32>(h, (size_t)node*HID + c0 + 8, &sF[e*360 + c*72 + part*16 + 8]);
        }
        __align__(16) u16 tmp[16];
        #pragma unroll
        for (int j = 0; j < 16; j++) tmp[j] = 0;
        if (part == 0) {
            float r2 = srad[e];
            tmp[0] = f2bf(r2);                           // kc0 = radial hi
            for (int j = 0; j < 15; j++)
                tmp[1+j] = f2bf(ldg1<F32>(a, (size_t)(e0+e)*EDGE_F + j));
        } else if (part == 1) {
            tmp[0] = f2bf(ldg1<F32>(a, (size_t)(e0+e)*EDGE_F + 15));
            float r2 = srad[e];
            tmp[1] = f2bf(r2 - bf2f(f2bf(r2)));          // kc17 = radial lo
        }
        *(uint4*)(&sF[e*360 + 4*72 + part*16])     = ((uint4*)tmp)[0];
        *(uint4*)(&sF[e*360 + 4*72 + part*16 + 8]) = ((uint4*)tmp)[1];
    }
    wave_lds_fence();

    // ---- GEMM1: K=320, B from global ----
    f32x4 acc1[10];
    #pragma unroll
    for (int nt = 0; nt < 10; nt++) {
        float v = bf2f(cbe1[nt*16 + col]);
        acc1[nt] = (f32x4){v, v, v, v};
    }
    const u16* fbase = &sF[(w*16 + col)*360];
    #pragma unroll
    for (int c = 0; c < 5; c++) {
        #pragma unroll
        for (int ks = 0; ks < 2; ks++) {
            short8 af = *(const short8*)(fbase + c*72 + ks*32 + q*8);
            const u16* B1 = We1Tb + (size_t)c*160*72 + ks*32 + q*8;
            #pragma unroll
            for (int nt = 0; nt < 10; nt++) {
                short8 b = *(const short8*)(B1 + (nt*16 + col)*72);
                acc1[nt] = __builtin_amdgcn_mfma_f32_16x16x32_bf16(af, b, acc1[nt], 0, 0, 0);
            }
        }
    }
    wave_lds_fence();                  // sF reads done before overwrite
    #pragma unroll
    for (int nt = 0; nt < 10; nt++)
        #pragma unroll
        for (int r = 0; r < 4; r++)
            sM1[(w*16 + q*4 + r)*168 + nt*16 + col] = f2bf(silu(acc1[nt][r]));
    wave_lds_fence();

    // ---- GEMM2: K=160 ----
    f32x4 acc2[10];
    #pragma unroll
    for (int nt = 0; nt < 10; nt++) {
        float v = bf2f(cbe2[nt*16 + col]);
        acc2[nt] = (f32x4){v, v, v, v};
    }
    const u16* m1base = &sM1[(w*16 + col)*168];
    #pragma unroll
    for (int k5 = 0; k5 < 5; k5++) {
        short8 af = *(const short8*)(m1base + k5*32 + q*8);
        const u16* B2 = We2Tb + (size_t)(k5>>1)*160*72 + (k5&1)*32 + q*8;
        #pragma unroll
        for (int nt = 0; nt < 10; nt++) {
            short8 b = *(const short8*)(B2 + (nt*16 + col)*72);
            acc2[nt] = __builtin_amdgcn_mfma_f32_16x16x32_bf16(af, b, acc2[nt], 0, 0, 0);
        }
    }
    // sM2 disjoint from sM1 -> no fence before writes
    #pragma unroll
    for (int nt = 0; nt < 10; nt++)
        #pragma unroll
        for (int r = 0; r < 4; r++)
            sM2[(w*16 + q*4 + r)*168 + nt*16 + col] = f2bf(silu(acc2[nt][r]));
    wave_lds_fence();

    // ---- GEMM3: N=144, K=160 ----
    f32x4 acc3[9];
    #pragma unroll
    for (int nt = 0; nt < 9; nt++) acc3[nt] = (f32x4){0.f, 0.f, 0.f, 0.f};
    const u16* m2base = &sM2[(w*16 + col)*168];
    #pragma unroll
    for (int k5 = 0; k5 < 5; k5++) {
        short8 af = *(const short8*)(m2base + k5*32 + q*8);
        const u16* B3 = W3Tb + (size_t)(k5>>1)*144*72 + (k5&1)*32 + q*8;
        #pragma unroll
        for (int nt = 0; nt < 9; nt++) {
            short8 b = *(const short8*)(B3 + (nt*16 + col)*72);
            acc3[nt] = __builtin_amdgcn_mfma_f32_16x16x32_bf16(af, b, acc3[nt], 0, 0, 0);
        }
    }

    // ---- epilogue (wave-local: shfl for ex, LDS meta for diff) ----
    int dstep[4];
    #pragma unroll
    for (int r = 0; r < 4; r++) dstep[r] = sdstl[w*16 + q*4 + r];

    float exv[4] = {0.f, 0.f, 0.f, 0.f};
    if (col < 8) {           // logits: head=col
        #pragma unroll
        for (int r = 0; r < 4; r++) {
            float ex = __expf(fminf(fmaxf(acc3[8][r], -30.f), 30.f));
            exv[r] = ex;
            atomicAdd(&den[(size_t)dstep[r]*8 + col], ex);
        }
    } else if (col == 8) {   // coord scalar
        #pragma unroll
        for (int r = 0; r < 4; r++) {
            int idx = w*16 + q*4 + r;
            int dd = dstep[r];
            float invf = sdiff[idx*4 + 3];
            float lc = fminf(fmaxf(acc3[8][r], -1e6f), 1e6f) * invf;
            #pragma unroll
            for (int j = 0; j < 3; j++)
                atomicAdd(&cacc[(size_t)dd*3 + j], lc * sdiff[idx*4 + j]);
        }
    }
    #pragma unroll
    for (int nt = 0; nt < 8; nt++) {
        float ex0 = __shfl(exv[0], q*16 + nt);
        float ex1 = __shfl(exv[1], q*16 + nt);
        float ex2 = __shfl(exv[2], q*16 + nt);
        float ex3 = __shfl(exv[3], q*16 + nt);
        atomicAdd(&hagg[(size_t)dstep[0]*HID + nt*16 + col], acc3[nt][0] * ex0);
        atomicAdd(&hagg[(size_t)dstep[1]*HID + nt*16 + col], acc3[nt][1] * ex1);
        atomicAdd(&hagg[(size_t)dstep[2]*HID + nt*16 + col], acc3[nt][2] * ex2);
        atomicAdd(&hagg[(size_t)dstep[3]*HID + nt*16 + col], acc3[nt][3] * ex3);
    }
}

__global__ __launch_bounds__(256, 3)
void edge_kernel(const int* __restrict__ flag,
                 const void* h, const void* coords, const void* a,
                 const int* __restrict__ src, const int* __restrict__ dst,
                 const u16* __restrict__ We1Tb, const u16* __restrict__ We2Tb,
                 const u16* __restrict__ W3Tb,
                 const u16* __restrict__ cbe1, const u16* __restrict__ cbe2,
                 float* __restrict__ den, float* __restrict__ hagg,
                 float* __restrict__ cacc)
{
    __shared__ __align__(16) u16 sPool[64*360];   // 46080 B
    __shared__ float sdiff[64*4];
    __shared__ float srad[64];
    __shared__ int   ssrc[64];
    __shared__ int   sdstl[64];
    if (*flag)
        edge_body<true>(h, coords, a, src, dst, We1Tb, We2Tb, W3Tb, cbe1, cbe2,
                        den, hagg, cacc, sPool, sdiff, srad, ssrc, sdstl);
    else
        edge_body<false>(h, coords, a, src, dst, We1Tb, We2Tb, W3Tb, cbe1, cbe2,
                         den, hagg, cacc, sPool, sdiff, srad, ssrc, sdstl);
}

// ---------------------------------------------------------------------------
// Barrier-free fused MFMA node kernel (unchanged from R7)
// ---------------------------------------------------------------------------
template<bool F32>
__device__ __forceinline__ void node_body(
    const void* h, const void* res, const void* coords, const void* y,
    const float* __restrict__ den, const float* __restrict__ hagg,
    const float* __restrict__ cacc,
    const u16* __restrict__ WoB, const u16* __restrict__ Wn1B,
    const u16* __restrict__ Wn2B, const u16* __restrict__ Wf1B,
    const u16* __restrict__ Wf2B,
    const u16* __restrict__ cbn1, const u16* __restrict__ cbn2,
    const u16* __restrict__ cbf1, const u16* __restrict__ cbf2,
    void* out, u16* sScr)
{
    const int t = threadIdx.x;
    const int w = t >> 6, l = t & 63, col = l & 15, q = l >> 4;
    const int nodew = blockIdx.x * 64 + w * 16;
    const int mynode = nodew + col;
    const bool okA = mynode < N_NODES;
    u16* sc = sScr + w * 16 * 168;

    int gm[4]; bool okC[4];
    #pragma unroll
    for (int r = 0; r < 4; r++) { gm[r] = nodew + q*4 + r; okC[r] = gm[r] < N_NODES; }

    f32x4 aF2[8];
    #pragma unroll
    for (int nt = 0; nt < 8; nt++) aF2[nt] = (f32x4){0.f,0.f,0.f,0.f};
    #pragma unroll
    for (int c = 0; c < 2; c++) {
        #pragma unroll
        for (int ks = 0; ks < 2; ks++) {
            const int kbase = c*64 + ks*32 + q*8;
            union { u16 s[8]; short8 v; } u;
            if (okA) {
                float dd = den[(size_t)mynode*8 + (kbase >> 4)];
                float inv = dd > 0.f ? 1.f/dd : 0.f;
                const float4* gp = (const float4*)(hagg + (size_t)mynode*HID + kbase);
                float4 v0 = gp[0], v1 = gp[1];
                u.s[0]=f2bf(v0.x*inv); u.s[1]=f2bf(v0.y*inv); u.s[2]=f2bf(v0.z*inv); u.s[3]=f2bf(v0.w*inv);
                u.s[4]=f2bf(v1.x*inv); u.s[5]=f2bf(v1.y*inv); u.s[6]=f2bf(v1.z*inv); u.s[7]=f2bf(v1.w*inv);
            } else {
                #pragma unroll
                for (int j = 0; j < 8; j++) u.s[j] = 0;
            }
            const u16* B = WoB + (size_t)c*128*72 + ks*32 + q*8;
            #pragma unroll
            for (int nt = 0; nt < 8; nt++) {
                short8 b = *(const short8*)(B + (nt*16 + col)*72);
                aF2[nt] = __builtin_amdgcn_mfma_f32_16x16x32_bf16(u.v, b, aF2[nt], 0, 0, 0);
            }
        }
    }

    f32x4 aFl[16];
    #pragma unroll
    for (int nt = 0; nt < 16; nt++) {
        float v = bf2f(cbf1[nt*16 + col]);
        aFl[nt] = (f32x4){v,v,v,v};
    }
    #pragma unroll
    for (int ks = 0; ks < 2; ks++) {
        short8 af;
        if (okA) af = ldfragA<F32>(y, (size_t)mynode*ADY + ks*32 + q*8);
        else { union { u16 s[8]; short8 v; } z; for (int j=0;j<8;j++) z.s[j]=0; af = z.v; }
        const u16* B = Wf1B + ks*32 + q*8;
        #pragma unroll
        for (int nt = 0; nt < 16; nt++) {
            short8 b = *(const short8*)(B + (nt*16 + col)*72);
            aFl[nt] = __builtin_amdgcn_mfma_f32_16x16x32_bf16(af, b, aFl[nt], 0, 0, 0);
        }
    }

    float h1c[8][4], r1c[8][4];
    {
        float xv[8][4], s[4], ss[4];
        #pragma unroll
        for (int r = 0; r < 4; r++) { s[r] = 0.f; ss[r] = 0.f; }
        #pragma unroll
        for (int nt = 0; nt < 8; nt++)
            #pragma unroll
            for (int r = 0; r < 4; r++) {
                float hv = okC[r] ? ldg1<F32>(h, (size_t)gm[r]*HID + nt*16 + col) : 0.f;
                float x = hv + aF2[nt][r];
                xv[nt][r] = x; s[r] += x; ss[r] += x*x;
            }
        #pragma unroll
        for (int r = 0; r < 4; r++)
            for (int off = 1; off <= 8; off <<= 1) {
                s[r]  += __shfl_xor(s[r], off);
                ss[r] += __shfl_xor(ss[r], off);
            }
        #pragma unroll
        for (int r = 0; r < 4; r++) {
            float mu = s[r] * (1.f/128.f);
            float var = ss[r] * (1.f/128.f) - mu*mu;
            float rs = rsqrtf(fmaxf(var, 0.f) + 1e-5f);
            #pragma unroll
            for (int nt = 0; nt < 8; nt++) {
                float h1 = (xv[nt][r]-mu)*rs*(1.f+aFl[nt][r]) + aFl[nt+8][r];
                h1c[nt][r] = h1;
                float rv = okC[r] ? ldg1<F32>(res, (size_t)gm[r]*HID + nt*16 + col) : 0.f;
                r1c[nt][r] = rv + aF2[nt][r];
                sc[(q*4 + r)*168 + nt*16 + col] = f2bf(h1);
            }
        }
    }
    wave_lds_fence();

    f32x4 aT[10];
    #pragma unroll
    for (int nt = 0; nt < 10; nt++) {
        float v = bf2f(cbn1[nt*16 + col]);
        aT[nt] = (f32x4){v,v,v,v};
    }
    #pragma unroll
    for (int c = 0; c < 2; c++) {
        #pragma unroll
        for (int ks = 0; ks < 2; ks++) {
            short8 af = *(const short8*)(sc + col*168 + c*64 + ks*32 + q*8);
            const u16* B = Wn1B + (size_t)c*160*72 + ks*32 + q*8;
            #pragma unroll
            for (int nt = 0; nt < 10; nt++) {
                short8 b = *(const short8*)(B + (nt*16 + col)*72);
                aT[nt] = __builtin_amdgcn_mfma_f32_16x16x32_bf16(af, b, aT[nt], 0, 0, 0);
            }
        }
    }
    wave_lds_fence();
    #pragma unroll
    for (int nt = 0; nt < 10; nt++)
        #pragma unroll
        for (int r = 0; r < 4; r++)
            sc[(q*4 + r)*168 + nt*16 + col] = f2bf(silu(aT[nt][r]));
    wave_lds_fence();

    f32x4 aF3[8];
    #pragma unroll
    for (int nt = 0; nt < 8; nt++) {
        float v = bf2f(cbn2[nt*16 + col]);
        aF3[nt] = (f32x4){v,v,v,v};
    }
    #pragma unroll
    for (int k5 = 0; k5 < 5; k5++) {
        short8 af = *(const short8*)(sc + col*168 + k5*32 + q*8);
        const u16* B = Wn2B + (size_t)(k5>>1)*128*72 + (k5&1)*32 + q*8;
        #pragma unroll
        for (int nt = 0; nt < 8; nt++) {
            short8 b = *(const short8*)(B + (nt*16 + col)*72);
            aF3[nt] = __builtin_amdgcn_mfma_f32_16x16x32_bf16(af, b, aF3[nt], 0, 0, 0);
        }
    }

    #pragma unroll
    for (int nt = 0; nt < 16; nt++) {
        float v = bf2f(cbf2[nt*16 + col]);
        aFl[nt] = (f32x4){v,v,v,v};
    }
    #pragma unroll
    for (int ks = 0; ks < 2; ks++) {
        short8 af;
        if (okA) af = ldfragA<F32>(y, (size_t)mynode*ADY + ks*32 + q*8);
        else { union { u16 s[8]; short8 v; } z; for (int j=0;j<8;j++) z.s[j]=0; af = z.v; }
        const u16* B = Wf2B + ks*32 + q*8;
        #pragma unroll
        for (int nt = 0; nt < 16; nt++) {
            short8 b = *(const short8*)(B + (nt*16 + col)*72);
            aFl[nt] = __builtin_amdgcn_mfma_f32_16x16x32_bf16(af, b, aFl[nt], 0, 0, 0);
        }
    }

    {
        float xv[8][4], s[4], ss[4];
        #pragma unroll
        for (int r = 0; r < 4; r++) { s[r] = 0.f; ss[r] = 0.f; }
        #pragma unroll
        for (int nt = 0; nt < 8; nt++)
            #pragma unroll
            for (int r = 0; r < 4; r++) {
                float x = h1c[nt][r] + aF3[nt][r];
                xv[nt][r] = x; s[r] += x; ss[r] += x*x;
            }
        #pragma unroll
        for (int r = 0; r < 4; r++)
            for (int off = 1; off <= 8; off <<= 1) {
                s[r]  += __shfl_xor(s[r], off);
                ss[r] += __shfl_xor(ss[r], off);
            }
        #pragma unroll
        for (int r = 0; r < 4; r++) {
            float mu = s[r] * (1.f/128.f);
            float var = ss[r] * (1.f/128.f) - mu*mu;
            float rs = rsqrtf(fmaxf(var, 0.f) + 1e-5f);
            if (okC[r]) {
                #pragma unroll
                for (int nt = 0; nt < 8; nt++) {
                    int n = nt*16 + col;
                    float h2 = (xv[nt][r]-mu)*rs*(1.f+aFl[nt][r]) + aFl[nt+8][r];
                    stg1<F32>(out, (size_t)gm[r]*HID + n, h2);
                    stg1<F32>(out, (size_t)OUT_RES + (size_t)gm[r]*HID + n,
                              r1c[nt][r] + aF3[nt][r]);
                }
            }
        }
    }

    if (q == 0 && okA) {
        #pragma unroll
        for (int j = 0; j < 3; j++)
            stg1<F32>(out, (size_t)OUT_CRD + (size_t)mynode*3 + j,
                      ldg1<F32>(coords, (size_t)mynode*3 + j) + cacc[(size_t)mynode*3 + j]);
    }
}

__global__ __launch_bounds__(256, 2)
void node_kernel(const int* __restrict__ flag,
                 const void* h, const void* res, const void* coords, const void* y,
                 const float* __restrict__ den, const float* __restrict__ hagg,
                 const float* __restrict__ cacc,
                 const u16* __restrict__ WoB, const u16* __restrict__ Wn1B,
                 const u16* __restrict__ Wn2B, const u16* __restrict__ Wf1B,
                 const u16* __restrict__ Wf2B,
                 const u16* __restrict__ cbn1, const u16* __restrict__ cbn2,
                 const u16* __restrict__ cbf1, const u16* __restrict__ cbf2,
                 void* out)
{
    __shared__ __align__(16) u16 sScr[4 * 16 * 168];
    if (*flag)
        node_body<true>(h, res, coords, y, den, hagg, cacc, WoB, Wn1B, Wn2B,
                        Wf1B, Wf2B, cbn1, cbn2, cbf1, cbf2, out, sScr);
    else
        node_body<false>(h, res, coords, y, den, hagg, cacc, WoB, Wn1B, Wn2B,
                         Wf1B, Wf2B, cbn1, cbn2, cbf1, cbf2, out, sScr);
}

// ---------------------------------------------------------------------------
extern "C" void kernel_launch(void* const* d_in, const int* in_sizes, int n_in,
                              void* d_out, int out_size, void* d_ws, size_t ws_size,
                              hipStream_t stream)
{
    const void* h      = d_in[0];
    const void* coords = d_in[1];
    const void* a      = d_in[2];
    const void* y      = d_in[3];
    const void* res    = d_in[4];
    const int* src     = (const int*)d_in[5];
    const int* dst     = (const int*)d_in[6];

    char* ws = (char*)d_ws;
    int*   flag = (int*)(ws + FLAG_OFF);
    float* den  = (float*)(ws + DEN_OFF);
    float* cacc = (float*)(ws + CACC_OFF);
    float* hagg = (float*)(ws + HAGG_OFF);

    const int wn[16]  = {43680, 25600, 20480, 1280, 160, 160, 160, 16384,
                         20480, 160, 20480, 128, 16384, 256, 16384, 256};
    const int widx[16] = {7, 9, 12, 13, 11, 8, 10, 14, 15, 16, 17, 18, 19, 20, 21, 22};
    u64 off = CW_BASE;
    CvtArgs args;
    u64 offs[16];
    for (int i = 0; i < 16; i++) {
        args.src[i] = d_in[widx[i]];
        args.dstoff[i] = off;
        args.n[i] = wn[i];
        offs[i] = off;
        off += (u64)wn[i] * 2;
    }
    u64 bw1 = (off + 255) & ~(u64)255;
    u64 bw2 = bw1 + (u64)5*160*72*2;
    u64 bw3 = bw2 + (u64)3*160*72*2;
    u64 bw4 = bw3 + (u64)3*144*72*2;
    u64 bw5 = bw4 + (u64)2*128*72*2;
    u64 bw6 = bw5 + (u64)2*160*72*2;
    u64 bw7 = bw6 + (u64)3*128*72*2;
    u64 bw8 = bw7 + (u64)256*72*2;

    const u16* cbe1 = (const u16*)(ws + offs[5]);
    const u16* cbe2 = (const u16*)(ws + offs[6]);
    const u16* cbn1 = (const u16*)(ws + offs[9]);
    const u16* cbn2 = (const u16*)(ws + offs[11]);
    const u16* cbf1 = (const u16*)(ws + offs[13]);
    const u16* cbf2 = (const u16*)(ws + offs[15]);
    const u16* We1Tb = (const u16*)(ws + bw1);
    const u16* We2Tb = (const u16*)(ws + bw2);
    const u16* W3Tb  = (const u16*)(ws + bw3);
    const u16* WoB   = (const u16*)(ws + bw4);
    const u16* Wn1B  = (const u16*)(ws + bw5);
    const u16* Wn2B  = (const u16*)(ws + bw6);
    const u16* Wf1B  = (const u16*)(ws + bw7);
    const u16* Wf2B  = (const u16*)(ws + bw8);

    hipMemsetAsync(d_ws, 0, MEMSET_BYTES, stream);

    detect_kernel<<<1, 256, 0, stream>>>(h, flag);
    cvt_kernel<<<dim3(8, 16), 256, 0, stream>>>(flag, ws, args);
    blockw_kernel<<<64, 256, 0, stream>>>(flag, ws, bw1, bw2, bw3, bw4,
                                          bw5, bw6, bw7, bw8,
                                          d_in[7], d_in[9], d_in[12], d_in[13], d_in[11],
                                          d_in[14], d_in[15], d_in[17], d_in[19], d_in[21]);

    edge_kernel<<<N_EDGES/64, 256, 0, stream>>>(flag, h, coords, a, src, dst,
                                                We1Tb, We2Tb, W3Tb, cbe1, cbe2,
                                                den, hagg, cacc);

    node_kernel<<<(N_NODES + 63)/64, 256, 0, stream>>>(
        flag, h, res, coords, y, den, hagg, cacc,
        WoB, Wn1B, Wn2B, Wf1B, Wf2B, cbn1, cbn2, cbf1, cbf2, d_out);
}